// Round 9
// baseline (249.840 us; speedup 1.0000x reference)
//
#include <hip/hip_runtime.h>

using int32x4 = __attribute__((ext_vector_type(4))) int;

#define BM 256
#define BN 256
#define ABUF 16384   // one A K-slab: 256 rows x 64B

// ---------------------------------------------------------------------------
// Kernel 1: pack int32 activations -> int8 (values in [-128,127])
// ---------------------------------------------------------------------------
__global__ __launch_bounds__(256) void pack_x_kernel(const int32x4* __restrict__ x,
                                                     int32x4* __restrict__ xp,
                                                     int nvec) {
    int t = blockIdx.x * 256 + threadIdx.x;
    if (t >= nvec) return;
    int32x4 a = x[t * 4 + 0];
    int32x4 b = x[t * 4 + 1];
    int32x4 c = x[t * 4 + 2];
    int32x4 d = x[t * 4 + 3];
    int32x4 o;
    o.x = (a.x & 255) | ((a.y & 255) << 8) | ((a.z & 255) << 16) | (a.w << 24);
    o.y = (b.x & 255) | ((b.y & 255) << 8) | ((b.z & 255) << 16) | (b.w << 24);
    o.z = (c.x & 255) | ((c.y & 255) << 8) | ((c.z & 255) << 16) | (c.w << 24);
    o.w = (d.x & 255) | ((d.y & 255) << 8) | ((d.z & 255) << 16) | (d.w << 24);
    xp[t] = o;
}

// ---------------------------------------------------------------------------
// Kernel 2: weight transform — int32 [K][N] -> int8 [N][K]
// ---------------------------------------------------------------------------
__global__ __launch_bounds__(256) void transform_w_kernel(const int* __restrict__ w,
                                                          unsigned char* __restrict__ wt,
                                                          int K, int N) {
    __shared__ unsigned char tileT[64][72];
    int tx = threadIdx.x & 15;
    int ty = threadIdx.x >> 4;
    int n0 = blockIdx.x * 64;
    int k0 = blockIdx.y * 64;
#pragma unroll
    for (int r = 0; r < 4; ++r) {
        int row = ty * 4 + r;  // k_local
        int32x4 v = *(const int32x4*)&w[(size_t)(k0 + row) * N + n0 + tx * 4];
        tileT[tx * 4 + 0][row] = (unsigned char)(v.x & 255);
        tileT[tx * 4 + 1][row] = (unsigned char)(v.y & 255);
        tileT[tx * 4 + 2][row] = (unsigned char)(v.z & 255);
        tileT[tx * 4 + 3][row] = (unsigned char)(v.w & 255);
    }
    __syncthreads();
#pragma unroll
    for (int r = 0; r < 4; ++r) {
        int row = ty * 4 + r;  // n_local
        uchar4 v = *(const uchar4*)&tileT[row][tx * 4];
        *(uchar4*)&wt[(size_t)(n0 + row) * K + k0 + tx * 4] = v;
    }
}

// ---------------------------------------------------------------------------
// Kernel 3: int8 GEMM, 256x256 tile. A staged in LDS (4-deep 16KB ring,
// verified 0-conflict fragment family); B fragments loaded DIRECTLY from
// global (L1/L2-resident panel) into reg double-buffer -> halves LDS traffic,
// which r6/r8 counters identified as the wall. One barrier per K-tile,
// wave-exact counted-vmcnt ledger.
// ---------------------------------------------------------------------------
__global__ __launch_bounds__(512, 2) void gemm_i8_bg(
    const char* __restrict__ A,   // [M][K] int8
    const char* __restrict__ Bt,  // [N][K] int8
    const int* __restrict__ bias,
    const int* __restrict__ shiftp,
    int* __restrict__ C,          // [M][N]
    int M, int N, int K) {
    __shared__ char smem[4 * ABUF];  // 64 KiB

    const int nbn = N / BN;
    const int nwg = gridDim.x;
    const int bid = blockIdx.x;
    const int cpx = nwg >> 3;  // nwg % 8 == 0 -> bijective XCD swizzle
    const int swz = (bid & 7) * cpx + (bid >> 3);
    const int m0 = (swz / nbn) * BM;
    const int n0 = (swz % nbn) * BN;

    const int t = threadIdx.x;
    const int lane = t & 63;
    const int wave = t >> 6;
    const int wr = wave >> 2;  // 0..1  (M half, 128 rows)
    const int wc = wave & 3;   // 0..3  (N quarter, 64 cols)

    // ---- A staging geometry (pre-swizzled global source, linear LDS dest) ----
    const int s_row = t >> 2;                                  // 0..127
    const int s_col = ((t & 3) << 4) ^ (((t >> 3) & 3) << 4);  // xor(row bits 1-2)
    const char* a_src = A + (size_t)(m0 + s_row) * K + s_col;
    const size_t jstr = (size_t)128 * K;
    char* lds_st = smem + t * 16;

    // ---- fragment-read geometry (verified 16-rows x 4-col-groups family) ----
    const int lr = lane & 15;
    const int lc = (lane >> 4) << 4;
    const int xr = ((lr >> 1) & 3) << 4;
    const int a_off = ((wr << 7) + lr) * 64 + (lc ^ xr);  // + mf*1024, mf 0..7

    // ---- B global-read geometry (same fragment mapping, no LDS) ----
    // lane l: row = n0 + wc*64 + nf*16 + (l&15), 16B at k-chunk (l>>4)
    const char* b_base = Bt + (size_t)(n0 + (wc << 6) + lr) * K + lc;
    const size_t n16 = (size_t)16 * K;

    int32x4 acc[8][4] = {};
    int32x4 afX[4], afY[4], bfX[4], bfY[4];

    const int nt = K / 64;  // 64 K-tiles (even, >= 6)

#define GLL(src, dst)                                                 \
    __builtin_amdgcn_global_load_lds(                                 \
        (const __attribute__((address_space(1))) void*)(src),        \
        (__attribute__((address_space(3))) void*)(dst), 16, 0, 0)

#define FENCE asm volatile("" ::: "memory")
#define BARR                           \
    do {                               \
        FENCE;                         \
        __builtin_amdgcn_s_barrier();  \
        FENCE;                         \
    } while (0)
#define SB0 __builtin_amdgcn_sched_barrier(0)
#define LGKM0                                                   \
    do {                                                        \
        asm volatile("s_waitcnt lgkmcnt(0)" ::: "memory");      \
        SB0;                                                    \
    } while (0)
#define VMW(n)                                                  \
    do {                                                        \
        asm volatile("s_waitcnt vmcnt(" #n ")" ::: "memory");   \
        SB0;                                                    \
    } while (0)

    // One K-tile. Entry: afX = A(TT, mf0-3) waited; BFC = B(TT) waited;
    // LDS ring holds A(TT), A(TT+1), A(TT+2).
    // Issue order (vmcnt events): [4x BFN global] [2x GLL A(TT+3)].
    // Steady tail VMW(2): drains BFN(TT+1) and A(TT+2) (older), leaves
    // A(TT+3) in flight. BARR then publishes A-ring state for tile TT+1.
#define TILE(TT, BFC, BFN, DOSTAGE, DOLOADB, DOREADN, WTAIL, DOBARR)                   \
    do {                                                                               \
        const int base_ = ((TT) & 3) * ABUF;                                           \
        const int nbase_ = (((TT) + 1) & 3) * ABUF;                                    \
        const int sb_ = (((TT) + 3) & 3) * ABUF;                                       \
        const size_t kg_ = (size_t)((TT) + 3) * 64;                                    \
        const size_t kb_ = (size_t)((TT) + 1) * 64;                                    \
        _Pragma("unroll") for (int i = 0; i < 4; ++i)                                  \
            afY[i] = *(const int32x4*)&smem[base_ + a_off + (4 + i) * 1024];           \
        if (DOLOADB) {                                                                 \
            _Pragma("unroll") for (int nf = 0; nf < 4; ++nf)                           \
                BFN[nf] = *(const int32x4*)(b_base + nf * n16 + kb_);                  \
        }                                                                              \
        if (DOSTAGE) {                                                                 \
            GLL(a_src + kg_, lds_st + sb_);                                            \
            GLL(a_src + jstr + kg_, lds_st + sb_ + 8192);                              \
        }                                                                              \
        SB0;                                                                           \
        __builtin_amdgcn_s_setprio(1);                                                 \
        _Pragma("unroll") for (int mi = 0; mi < 4; ++mi)                               \
            _Pragma("unroll") for (int ni = 0; ni < 4; ++ni)                           \
                acc[mi][ni] = __builtin_amdgcn_mfma_i32_16x16x64_i8(                   \
                    afX[mi], BFC[ni], acc[mi][ni], 0, 0, 0);                           \
        __builtin_amdgcn_s_setprio(0);                                                 \
        LGKM0; /* afY landed under burst 1 */                                          \
        if (DOREADN) {                                                                 \
            _Pragma("unroll") for (int i = 0; i < 4; ++i)                              \
                afX[i] = *(const int32x4*)&smem[nbase_ + a_off + i * 1024];            \
        }                                                                              \
        SB0;                                                                           \
        __builtin_amdgcn_s_setprio(1);                                                 \
        _Pragma("unroll") for (int mi = 0; mi < 4; ++mi)                               \
            _Pragma("unroll") for (int ni = 0; ni < 4; ++ni)                           \
                acc[4 + mi][ni] = __builtin_amdgcn_mfma_i32_16x16x64_i8(               \
                    afY[mi], BFC[ni], acc[4 + mi][ni], 0, 0, 0);                       \
        __builtin_amdgcn_s_setprio(0);                                                 \
        if (DOREADN) LGKM0; /* next afX landed under burst 2 */                        \
        WTAIL;                                                                         \
        if (DOBARR) BARR;                                                              \
    } while (0)

    // ---- prologue: stage A tiles 0,1,2 into bufs 0,1,2; load B(0) ----
#pragma unroll
    for (int p = 0; p < 3; ++p) {
        GLL(a_src + p * 64, lds_st + p * ABUF);
        GLL(a_src + jstr + p * 64, lds_st + p * ABUF + 8192);
    }
#pragma unroll
    for (int nf = 0; nf < 4; ++nf) bfX[nf] = *(const int32x4*)(b_base + nf * n16);
    VMW(0);  // drain all prologue staging + B(0)
    BARR;
    // preload afX = A(0, mf0-3) from buf0
#pragma unroll
    for (int i = 0; i < 4; ++i) afX[i] = *(const int32x4*)&smem[a_off + i * 1024];
    LGKM0;

    // ---- main loop ----
    int tt = 0;
    for (; tt < nt - 4; tt += 2) {
        TILE(tt, bfX, bfY, 1, 1, 1, VMW(2), 1);
        TILE(tt + 1, bfY, bfX, 1, 1, 1, VMW(2), 1);
    }
    // tt == nt-4 (even): last tile that still stages A(nt-1)
    TILE(nt - 4, bfX, bfY, 1, 1, 1, VMW(2), 1);
    TILE(nt - 3, bfY, bfX, 0, 1, 1, VMW(0), 1);   // drains A(nt-1) + B(nt-2)
    TILE(nt - 2, bfX, bfY, 0, 1, 1, VMW(0), 1);   // drains B(nt-1)
    TILE(nt - 1, bfY, bfX, 0, 0, 0, (void)0, 0);  // last tile

    // ---- epilogue: bias + shift, int32 store (16x16 C/D layout) ----
    const int s = *shiftp;
    const int crow = (lane >> 4) << 2;
    const int ccol = lane & 15;
    int bv[4];
#pragma unroll
    for (int nf = 0; nf < 4; ++nf) bv[nf] = bias[n0 + wc * 64 + nf * 16 + ccol];
#pragma unroll
    for (int mf = 0; mf < 8; ++mf) {
        const int grow0 = m0 + wr * 128 + mf * 16 + crow;
#pragma unroll
        for (int nf = 0; nf < 4; ++nf) {
            const int gcol = n0 + wc * 64 + nf * 16 + ccol;
#pragma unroll
            for (int r = 0; r < 4; ++r) {
                int y = acc[mf][nf][r] + bv[nf];
                y = (s > 0) ? (y >> s) : y;
                C[(size_t)(grow0 + r) * N + gcol] = y;
            }
        }
    }
#undef GLL
#undef FENCE
#undef BARR
#undef SB0
#undef LGKM0
#undef VMW
#undef TILE
}

// ---------------------------------------------------------------------------
extern "C" void kernel_launch(void* const* d_in, const int* in_sizes, int n_in,
                              void* d_out, int out_size, void* d_ws, size_t ws_size,
                              hipStream_t stream) {
    const int* x = (const int*)d_in[0];
    const int* w = (const int*)d_in[1];   // int8 values stored as int32
    const int* bias = (const int*)d_in[2];
    const int* shiftp = (const int*)d_in[3];
    int* out = (int*)d_out;

    const int N = in_sizes[2];      // 4096
    const int K = in_sizes[1] / N;  // 4096
    const int M = in_sizes[0] / K;  // 8192

    char* xp = (char*)d_ws;
    unsigned char* wt = (unsigned char*)d_ws + (size_t)M * K;

    int nvec = (int)(((long long)M * K) / 16);
    pack_x_kernel<<<(nvec + 255) / 256, 256, 0, stream>>>((const int32x4*)x, (int32x4*)xp, nvec);

    dim3 tgrid(N / 64, K / 64);
    transform_w_kernel<<<tgrid, 256, 0, stream>>>(w, wt, K, N);

    int nwg = (M / BM) * (N / BN);  // 512, %8==0
    gemm_i8_bg<<<nwg, 512, 0, stream>>>(xp, (const char*)wt, bias, shiftp, out, M, N, K);
}

// Round 10
// 184.926 us; speedup vs baseline: 1.3510x; 1.3510x over previous
//
#include <hip/hip_runtime.h>

using int32x4 = __attribute__((ext_vector_type(4))) int;

#define BM 256
#define BN 256
#define TBUF 32768   // one K-tile buffer: A(16K) + B(16K); K-tile = 64 bytes of K

// ---------------------------------------------------------------------------
// Kernel 1: pack int32 activations -> int8 (values in [-128,127])
// ---------------------------------------------------------------------------
__global__ __launch_bounds__(256) void pack_x_kernel(const int32x4* __restrict__ x,
                                                     int32x4* __restrict__ xp,
                                                     int nvec) {
    int t = blockIdx.x * 256 + threadIdx.x;
    if (t >= nvec) return;
    int32x4 a = x[t * 4 + 0];
    int32x4 b = x[t * 4 + 1];
    int32x4 c = x[t * 4 + 2];
    int32x4 d = x[t * 4 + 3];
    int32x4 o;
    o.x = (a.x & 255) | ((a.y & 255) << 8) | ((a.z & 255) << 16) | (a.w << 24);
    o.y = (b.x & 255) | ((b.y & 255) << 8) | ((b.z & 255) << 16) | (b.w << 24);
    o.z = (c.x & 255) | ((c.y & 255) << 8) | ((c.z & 255) << 16) | (c.w << 24);
    o.w = (d.x & 255) | ((d.y & 255) << 8) | ((d.z & 255) << 16) | (d.w << 24);
    xp[t] = o;
}

// ---------------------------------------------------------------------------
// Kernel 2: weight transform — int32 [K][N] -> int8 [N][K]
// ---------------------------------------------------------------------------
__global__ __launch_bounds__(256) void transform_w_kernel(const int* __restrict__ w,
                                                          unsigned char* __restrict__ wt,
                                                          int K, int N) {
    __shared__ unsigned char tileT[64][72];
    int tx = threadIdx.x & 15;
    int ty = threadIdx.x >> 4;
    int n0 = blockIdx.x * 64;
    int k0 = blockIdx.y * 64;
#pragma unroll
    for (int r = 0; r < 4; ++r) {
        int row = ty * 4 + r;  // k_local
        int32x4 v = *(const int32x4*)&w[(size_t)(k0 + row) * N + n0 + tx * 4];
        tileT[tx * 4 + 0][row] = (unsigned char)(v.x & 255);
        tileT[tx * 4 + 1][row] = (unsigned char)(v.y & 255);
        tileT[tx * 4 + 2][row] = (unsigned char)(v.z & 255);
        tileT[tx * 4 + 3][row] = (unsigned char)(v.w & 255);
    }
    __syncthreads();
#pragma unroll
    for (int r = 0; r < 4; ++r) {
        int row = ty * 4 + r;  // n_local
        uchar4 v = *(const uchar4*)&tileT[row][tx * 4];
        *(uchar4*)&wt[(size_t)(n0 + row) * K + k0 + tx * 4] = v;
    }
}

// ---------------------------------------------------------------------------
// Kernel 3: int8 GEMM, 256x256 tile, 16x16x64 MFMA (verified 0-conflict
// family). r6 schedule (1 mid-tile barrier, reg-dbuf fragments, setprio)
// + r4 ledger (4-deep LDS ring, stage t+3, counted VMW(4) -- issue->wait
// ~1.8 tiles >> HBM latency, no same-tile vmcnt drain).
// ---------------------------------------------------------------------------
__global__ __launch_bounds__(512, 2) void gemm_i8_d4(
    const char* __restrict__ A,   // [M][K] int8
    const char* __restrict__ Bt,  // [N][K] int8
    const int* __restrict__ bias,
    const int* __restrict__ shiftp,
    int* __restrict__ C,          // [M][N]
    int M, int N, int K) {
    __shared__ char smem[4 * TBUF];  // 128 KiB

    const int nbn = N / BN;
    const int nwg = gridDim.x;
    const int bid = blockIdx.x;
    const int cpx = nwg >> 3;  // nwg % 8 == 0 -> bijective XCD swizzle
    const int swz = (bid & 7) * cpx + (bid >> 3);
    const int m0 = (swz / nbn) * BM;
    const int n0 = (swz % nbn) * BN;

    const int t = threadIdx.x;
    const int lane = t & 63;
    const int wave = t >> 6;
    const int wr = wave >> 2;  // 0..1  (M half, 128 rows)
    const int wc = wave & 3;   // 0..3  (N quarter, 64 cols)

    // ---- staging geometry (pre-swizzled global source, linear LDS dest) ----
    const int s_row = t >> 2;
    const int s_col = ((t & 3) << 4) ^ (((t >> 3) & 3) << 4);
    const char* a_src = A + (size_t)(m0 + s_row) * K + s_col;
    const char* b_src = Bt + (size_t)(n0 + s_row) * K + s_col;
    const size_t jstr = (size_t)128 * K;
    char* lds_st = smem + t * 16;

    // ---- fragment-read geometry (verified 16-rows x 4-col-groups family) ----
    const int lr = lane & 15;
    const int lc = (lane >> 4) << 4;
    const int xr = ((lr >> 1) & 3) << 4;
    const int a_off = ((wr << 7) + lr) * 64 + (lc ^ xr);          // + mf*1024
    const int b_off = 16384 + ((wc << 6) + lr) * 64 + (lc ^ xr);  // + nf*1024

    int32x4 acc[8][4] = {};
    int32x4 afX[4], afY[4], bfX[4], bfY[4];

    const int nt = K / 64;  // 64 K-tiles (even, >= 8)

#define GLL(src, dst)                                                 \
    __builtin_amdgcn_global_load_lds(                                 \
        (const __attribute__((address_space(1))) void*)(src),        \
        (__attribute__((address_space(3))) void*)(dst), 16, 0, 0)

#define FENCE asm volatile("" ::: "memory")
#define BARR                           \
    do {                               \
        FENCE;                         \
        __builtin_amdgcn_s_barrier();  \
        FENCE;                         \
    } while (0)
#define SB0 __builtin_amdgcn_sched_barrier(0)
#define LGKM0                                                   \
    do {                                                        \
        asm volatile("s_waitcnt lgkmcnt(0)" ::: "memory");      \
        SB0;                                                    \
    } while (0)
#define VMW(n)                                                  \
    do {                                                        \
        asm volatile("s_waitcnt vmcnt(" #n ")" ::: "memory");   \
        SB0;                                                    \
    } while (0)

    // One K-tile TT (r6 order, 4-deep ledger):
    //   1. afY reads (buf TT)
    //   2. burst1 (afX x BFC)          -- afX/BFC loaded last tile
    //   3. LGKM0                        -- all buf-TT reads of THIS wave landed
    //   4. WDRAIN: VMW(4) drains stage(TT+1) [issued step 6 of tile TT-2,
    //      ~1.8 tiles ago]; leaves stage(TT+2) in flight
    //   5. BARR -- publishes stage(TT+1); licenses overwrite of buf (TT+3)&3
    //      (its readers all landed before the PREVIOUS barrier)
    //   6. GLL stage(TT+3) -> buf (TT+3)&3
    //   7. readN: afX', BFN from buf (TT+1)&3
    //   8. burst2 (afY x BFC); LGKM0
#define TILE(TT, BFC, BFN, DOSTAGE, DOREADN, WDRAIN)                                   \
    do {                                                                               \
        const int base_ = ((TT) & 3) * TBUF;                                           \
        const int nbase_ = (((TT) + 1) & 3) * TBUF;                                    \
        const int sb_ = (((TT) + 3) & 3) * TBUF;                                       \
        const size_t kc_ = (size_t)((TT) + 3) * 64;                                    \
        _Pragma("unroll") for (int i = 0; i < 4; ++i)                                  \
            afY[i] = *(const int32x4*)&smem[base_ + a_off + (4 + i) * 1024];           \
        SB0;                                                                           \
        __builtin_amdgcn_s_setprio(1);                                                 \
        _Pragma("unroll") for (int mi = 0; mi < 4; ++mi)                               \
            _Pragma("unroll") for (int ni = 0; ni < 4; ++ni)                           \
                acc[mi][ni] = __builtin_amdgcn_mfma_i32_16x16x64_i8(                   \
                    afX[mi], BFC[ni], acc[mi][ni], 0, 0, 0);                           \
        __builtin_amdgcn_s_setprio(0);                                                 \
        LGKM0;                                                                         \
        WDRAIN;                                                                        \
        BARR;                                                                          \
        if (DOSTAGE) {                                                                 \
            GLL(a_src + kc_, lds_st + sb_);                                            \
            GLL(a_src + jstr + kc_, lds_st + sb_ + 8192);                              \
            GLL(b_src + kc_, lds_st + sb_ + 16384);                                    \
            GLL(b_src + jstr + kc_, lds_st + sb_ + 24576);                             \
        }                                                                              \
        if (DOREADN) {                                                                 \
            _Pragma("unroll") for (int i = 0; i < 4; ++i)                              \
                afX[i] = *(const int32x4*)&smem[nbase_ + a_off + i * 1024];            \
            _Pragma("unroll") for (int i = 0; i < 4; ++i)                              \
                BFN[i] = *(const int32x4*)&smem[nbase_ + b_off + i * 1024];            \
        }                                                                              \
        SB0;                                                                           \
        __builtin_amdgcn_s_setprio(1);                                                 \
        _Pragma("unroll") for (int mi = 0; mi < 4; ++mi)                               \
            _Pragma("unroll") for (int ni = 0; ni < 4; ++ni)                           \
                acc[4 + mi][ni] = __builtin_amdgcn_mfma_i32_16x16x64_i8(               \
                    afY[mi], BFC[ni], acc[4 + mi][ni], 0, 0, 0);                       \
        __builtin_amdgcn_s_setprio(0);                                                 \
        if (DOREADN) LGKM0;                                                            \
    } while (0)

    // ---- prologue: stage tiles 0,1,2 into bufs 0,1,2 (tile order) ----
#pragma unroll
    for (int p = 0; p < 3; ++p) {
        GLL(a_src + p * 64, lds_st + p * TBUF);
        GLL(a_src + jstr + p * 64, lds_st + p * TBUF + 8192);
        GLL(b_src + p * 64, lds_st + p * TBUF + 16384);
        GLL(b_src + jstr + p * 64, lds_st + p * TBUF + 24576);
    }
    VMW(8);  // own stage(0) done; stage(1), stage(2) in flight
    BARR;    // all waves' stage(0) published
    // preload X(0) from buf0
#pragma unroll
    for (int i = 0; i < 4; ++i) afX[i] = *(const int32x4*)&smem[a_off + i * 1024];
#pragma unroll
    for (int i = 0; i < 4; ++i) bfX[i] = *(const int32x4*)&smem[b_off + i * 1024];
    LGKM0;

    // ---- main loop ----
    // Steady state: tile t drains stage(t+1) at step 4 (outstanding there =
    // {stage(t+1), stage(t+2)} = 8 -> VMW(4)), stages (t+3) at step 6.
    int tt = 0;
    for (; tt < nt - 4; tt += 2) {
        TILE(tt, bfX, bfY, 1, 1, VMW(4));
        TILE(tt + 1, bfY, bfX, 1, 1, VMW(4));
    }
    // peel (nt even): tiles nt-4 .. nt-1
    TILE(nt - 4, bfX, bfY, 1, 1, VMW(4));   // stages tile nt-1; drains stage(nt-3)
    TILE(nt - 3, bfY, bfX, 0, 1, VMW(4));   // drains stage(nt-2); leaves stage(nt-1)
    TILE(nt - 2, bfX, bfY, 0, 1, VMW(0));   // drains stage(nt-1) for step-7 reads
    TILE(nt - 1, bfY, bfX, 0, 0, (void)0);  // last tile

    // ---- epilogue: bias + shift, int32 store (16x16 C/D layout) ----
    const int s = *shiftp;
    const int crow = (lane >> 4) << 2;
    const int ccol = lane & 15;
    int bv[4];
#pragma unroll
    for (int nf = 0; nf < 4; ++nf) bv[nf] = bias[n0 + wc * 64 + nf * 16 + ccol];
#pragma unroll
    for (int mf = 0; mf < 8; ++mf) {
        const int grow0 = m0 + wr * 128 + mf * 16 + crow;
#pragma unroll
        for (int nf = 0; nf < 4; ++nf) {
            const int gcol = n0 + wc * 64 + nf * 16 + ccol;
#pragma unroll
            for (int r = 0; r < 4; ++r) {
                int y = acc[mf][nf][r] + bv[nf];
                y = (s > 0) ? (y >> s) : y;
                C[(size_t)(grow0 + r) * N + gcol] = y;
            }
        }
    }
#undef GLL
#undef FENCE
#undef BARR
#undef SB0
#undef LGKM0
#undef VMW
#undef TILE
}

// ---------------------------------------------------------------------------
extern "C" void kernel_launch(void* const* d_in, const int* in_sizes, int n_in,
                              void* d_out, int out_size, void* d_ws, size_t ws_size,
                              hipStream_t stream) {
    const int* x = (const int*)d_in[0];
    const int* w = (const int*)d_in[1];   // int8 values stored as int32
    const int* bias = (const int*)d_in[2];
    const int* shiftp = (const int*)d_in[3];
    int* out = (int*)d_out;

    const int N = in_sizes[2];      // 4096
    const int K = in_sizes[1] / N;  // 4096
    const int M = in_sizes[0] / K;  // 8192

    char* xp = (char*)d_ws;
    unsigned char* wt = (unsigned char*)d_ws + (size_t)M * K;

    int nvec = (int)(((long long)M * K) / 16);
    pack_x_kernel<<<(nvec + 255) / 256, 256, 0, stream>>>((const int32x4*)x, (int32x4*)xp, nvec);

    dim3 tgrid(N / 64, K / 64);
    transform_w_kernel<<<tgrid, 256, 0, stream>>>(w, wt, K, N);

    int nwg = (M / BM) * (N / BN);  // 512, %8==0
    gemm_i8_d4<<<nwg, 512, 0, stream>>>(xp, (const char*)wt, bias, shiftp, out, M, N, K);
}

// Round 11
// 184.913 us; speedup vs baseline: 1.3511x; 1.0001x over previous
//
#include <hip/hip_runtime.h>

using int32x4 = __attribute__((ext_vector_type(4))) int;

#define BM 256
#define BN 256
#define MBUF 65536   // one mega-tile buffer: A 32K (256r x 128B) + B 32K

// ---------------------------------------------------------------------------
// Kernel 1: pack int32 activations -> int8 (values in [-128,127])
// ---------------------------------------------------------------------------
__global__ __launch_bounds__(256) void pack_x_kernel(const int32x4* __restrict__ x,
                                                     int32x4* __restrict__ xp,
                                                     int nvec) {
    int t = blockIdx.x * 256 + threadIdx.x;
    if (t >= nvec) return;
    int32x4 a = x[t * 4 + 0];
    int32x4 b = x[t * 4 + 1];
    int32x4 c = x[t * 4 + 2];
    int32x4 d = x[t * 4 + 3];
    int32x4 o;
    o.x = (a.x & 255) | ((a.y & 255) << 8) | ((a.z & 255) << 16) | (a.w << 24);
    o.y = (b.x & 255) | ((b.y & 255) << 8) | ((b.z & 255) << 16) | (b.w << 24);
    o.z = (c.x & 255) | ((c.y & 255) << 8) | ((c.z & 255) << 16) | (c.w << 24);
    o.w = (d.x & 255) | ((d.y & 255) << 8) | ((d.z & 255) << 16) | (d.w << 24);
    xp[t] = o;
}

// ---------------------------------------------------------------------------
// Kernel 2: weight transform — int32 [K][N] -> int8 [N][K]
// ---------------------------------------------------------------------------
__global__ __launch_bounds__(256) void transform_w_kernel(const int* __restrict__ w,
                                                          unsigned char* __restrict__ wt,
                                                          int K, int N) {
    __shared__ unsigned char tileT[64][72];
    int tx = threadIdx.x & 15;
    int ty = threadIdx.x >> 4;
    int n0 = blockIdx.x * 64;
    int k0 = blockIdx.y * 64;
#pragma unroll
    for (int r = 0; r < 4; ++r) {
        int row = ty * 4 + r;  // k_local
        int32x4 v = *(const int32x4*)&w[(size_t)(k0 + row) * N + n0 + tx * 4];
        tileT[tx * 4 + 0][row] = (unsigned char)(v.x & 255);
        tileT[tx * 4 + 1][row] = (unsigned char)(v.y & 255);
        tileT[tx * 4 + 2][row] = (unsigned char)(v.z & 255);
        tileT[tx * 4 + 3][row] = (unsigned char)(v.w & 255);
    }
    __syncthreads();
#pragma unroll
    for (int r = 0; r < 4; ++r) {
        int row = ty * 4 + r;  // n_local
        uchar4 v = *(const uchar4*)&tileT[row][tx * 4];
        *(uchar4*)&wt[(size_t)(n0 + row) * K + k0 + tx * 4] = v;
    }
}

// ---------------------------------------------------------------------------
// Kernel 3: int8 GEMM, 256x256 tile, BK=128 mega-tiles, 2-deep 64KiB LDS
// buffers, woven body (24 ds_read interleaved with 4x16 MFMA, counted lgkm),
// 2 barriers + 1 counted vmcnt per 128B of K. 128B-row XOR swizzle
// (byte bits 4-6 ^= row&7; pre-swizzled global source, linear GLL dest).
// ---------------------------------------------------------------------------
__global__ __launch_bounds__(512, 2) void gemm_i8_mega(
    const char* __restrict__ A,   // [M][K] int8
    const char* __restrict__ Bt,  // [N][K] int8
    const int* __restrict__ bias,
    const int* __restrict__ shiftp,
    int* __restrict__ C,          // [M][N]
    int M, int N, int K) {
    __shared__ char smem[2 * MBUF];  // 128 KiB

    const int nbn = N / BN;
    const int nwg = gridDim.x;
    const int bid = blockIdx.x;
    const int cpx = nwg >> 3;  // nwg % 8 == 0 -> bijective XCD swizzle
    const int swz = (bid & 7) * cpx + (bid >> 3);
    const int m0 = (swz / nbn) * BM;
    const int n0 = (swz % nbn) * BN;

    const int t = threadIdx.x;
    const int lane = t & 63;
    const int wave = t >> 6;
    const int wr = wave >> 2;  // 0..1  (M half, 128 rows)
    const int wc = wave & 3;   // 0..3  (N quarter, 64 cols)

    // ---- staging geometry ----
    // LDS linear: chunk j (8KB = 64 rows x 128B): byte = j*8192 + t*16
    //   -> row = j*64 + (t>>3), col = (t&7)*16
    // source col = col ^ ((row&7)<<4) = (((t&7) ^ ((t>>3)&7)) << 4)
    const int s_row = t >> 3;                                 // 0..63
    const int s_col = (((t & 7) ^ ((t >> 3) & 7)) << 4);
    const char* a_src = A + (size_t)(m0 + s_row) * K + s_col;
    const char* b_src = Bt + (size_t)(n0 + s_row) * K + s_col;
    const size_t jstr = (size_t)64 * K;  // 64 rows per GLL chunk
    char* lds_st = smem + t * 16;

    // ---- fragment-read geometry (128B rows, swz = (row&7)<<4) ----
    const int lr = lane & 15;
    const int lc = (lane >> 4) << 4;   // 0,16,32,48
    const int xr = (lr & 7) << 4;
    const int rowA = (wr << 7) + lr;          // + mf*16 (mf*16 % 8 == 0)
    const int rowB = (wc << 6) + lr;          // + nf*16
    const int a_s0 = rowA * 128 + (lc ^ xr);           // + mf*2048
    const int a_s1 = rowA * 128 + ((lc | 64) ^ xr);
    const int b_s0 = 32768 + rowB * 128 + (lc ^ xr);   // + nf*2048
    const int b_s1 = 32768 + rowB * 128 + ((lc | 64) ^ xr);

    int32x4 acc[8][4] = {};
    int32x4 afX[4], afY[4], bfX[4], bfY[4];

    const int nt = K / 128;  // 32 mega-tiles (even)

#define GLL(src, dst)                                                 \
    __builtin_amdgcn_global_load_lds(                                 \
        (const __attribute__((address_space(1))) void*)(src),        \
        (__attribute__((address_space(3))) void*)(dst), 16, 0, 0)

#define FENCE asm volatile("" ::: "memory")
#define BARR                           \
    do {                               \
        FENCE;                         \
        __builtin_amdgcn_s_barrier();  \
        FENCE;                         \
    } while (0)
#define SB0 __builtin_amdgcn_sched_barrier(0)
#define LGKM(n)                                                   \
    do {                                                          \
        asm volatile("s_waitcnt lgkmcnt(" #n ")" ::: "memory");   \
        SB0;                                                      \
    } while (0)
#define VMW(n)                                                  \
    do {                                                        \
        asm volatile("s_waitcnt vmcnt(" #n ")" ::: "memory");   \
        SB0;                                                    \
    } while (0)

    // stage mega-tile TT into buffer BUF (8 GLL: 4 A-chunks, 4 B-chunks)
#define STAGE8(TT, BUF)                                                    \
    do {                                                                   \
        const size_t kc_ = (size_t)(TT) * 128;                             \
        _Pragma("unroll") for (int j = 0; j < 4; ++j)                      \
            GLL(a_src + kc_ + j * jstr, lds_st + (BUF) + j * 8192);        \
        _Pragma("unroll") for (int j = 0; j < 4; ++j)                      \
            GLL(b_src + kc_ + j * jstr, lds_st + (BUF) + 32768 + j * 8192);\
    } while (0)

#define MFMA_B(ACCROW, AF, BF)                                                   \
    do {                                                                         \
        __builtin_amdgcn_s_setprio(1);                                           \
        _Pragma("unroll") for (int mi = 0; mi < 4; ++mi)                         \
            _Pragma("unroll") for (int ni = 0; ni < 4; ++ni)                     \
                acc[(ACCROW) + mi][ni] = __builtin_amdgcn_mfma_i32_16x16x64_i8(  \
                    AF[mi], BF[ni], acc[(ACCROW) + mi][ni], 0, 0, 0);            \
        __builtin_amdgcn_s_setprio(0);                                           \
    } while (0)

    // Woven mega-tile body: 24 ds_read + 4x16 MFMA, counted lgkm.
    // DS completes in order: issue 16 -> LGKM(8) waits afX,bfX only.
#define BODY(BUF)                                                                \
    do {                                                                         \
        _Pragma("unroll") for (int i = 0; i < 4; ++i)                            \
            afX[i] = *(const int32x4*)&smem[(BUF) + a_s0 + i * 2048];            \
        _Pragma("unroll") for (int i = 0; i < 4; ++i)                            \
            bfX[i] = *(const int32x4*)&smem[(BUF) + b_s0 + i * 2048];            \
        _Pragma("unroll") for (int i = 0; i < 4; ++i)                            \
            afY[i] = *(const int32x4*)&smem[(BUF) + a_s0 + (4 + i) * 2048];      \
        _Pragma("unroll") for (int i = 0; i < 4; ++i)                            \
            bfY[i] = *(const int32x4*)&smem[(BUF) + b_s1 + i * 2048];            \
        LGKM(8);  /* afX,bfX ready; afY,bfY in flight */                         \
        MFMA_B(0, afX, bfX);                                                     \
        LGKM(4);  /* afY ready */                                                \
        _Pragma("unroll") for (int i = 0; i < 4; ++i)                            \
            afX[i] = *(const int32x4*)&smem[(BUF) + a_s1 + i * 2048];            \
        MFMA_B(4, afY, bfX);                                                     \
        LGKM(4);  /* bfY ready (afX-s1 in flight) */                             \
        _Pragma("unroll") for (int i = 0; i < 4; ++i)                            \
            afY[i] = *(const int32x4*)&smem[(BUF) + a_s1 + (4 + i) * 2048];      \
        LGKM(4);  /* afX-s1 ready (afY-s1 in flight) */                          \
        MFMA_B(0, afX, bfY);                                                     \
        LGKM(0);  /* afY-s1 ready */                                             \
        MFMA_B(4, afY, bfY);                                                     \
    } while (0)

    // ---- prologue: stage tiles 0 (buf0) and 1 (buf1) ----
    STAGE8(0, 0);
    STAGE8(1, MBUF);
    VMW(8);  // own stage(0) chunks done; stage(1) in flight
    BARR;    // stage(0) published

    // ---- main loop (2 mega-tiles per iteration; bases compile-time) ----
    for (int tt = 0; tt < nt - 2; tt += 2) {
        BODY(0);
        BARR;               // all waves done reading buf0
        STAGE8(tt + 2, 0);  // restage buf0 with tile tt+2
        VMW(8);             // drain stage(tt+1) (issued one full tile ago)
        BARR;               // publish stage(tt+1)
        BODY(MBUF);
        BARR;
        STAGE8(tt + 3, MBUF);
        VMW(8);             // drain stage(tt+2)
        BARR;
    }
    // tail: tiles nt-2 (buf0), nt-1 (buf1); only stage(nt-1) outstanding
    BODY(0);
    BARR;
    VMW(0);  // drain stage(nt-1)
    BARR;
    BODY(MBUF);

    // ---- epilogue: bias + shift, int32 store (16x16 C/D layout) ----
    const int s = *shiftp;
    const int crow = (lane >> 4) << 2;
    const int ccol = lane & 15;
    int bv[4];
#pragma unroll
    for (int nf = 0; nf < 4; ++nf) bv[nf] = bias[n0 + wc * 64 + nf * 16 + ccol];
#pragma unroll
    for (int mf = 0; mf < 8; ++mf) {
        const int grow0 = m0 + wr * 128 + mf * 16 + crow;
#pragma unroll
        for (int nf = 0; nf < 4; ++nf) {
            const int gcol = n0 + wc * 64 + nf * 16 + ccol;
#pragma unroll
            for (int r = 0; r < 4; ++r) {
                int y = acc[mf][nf][r] + bv[nf];
                y = (s > 0) ? (y >> s) : y;
                C[(size_t)(grow0 + r) * N + gcol] = y;
            }
        }
    }
#undef GLL
#undef FENCE
#undef BARR
#undef SB0
#undef LGKM
#undef VMW
#undef STAGE8
#undef MFMA_B
#undef BODY
}

// ---------------------------------------------------------------------------
extern "C" void kernel_launch(void* const* d_in, const int* in_sizes, int n_in,
                              void* d_out, int out_size, void* d_ws, size_t ws_size,
                              hipStream_t stream) {
    const int* x = (const int*)d_in[0];
    const int* w = (const int*)d_in[1];   // int8 values stored as int32
    const int* bias = (const int*)d_in[2];
    const int* shiftp = (const int*)d_in[3];
    int* out = (int*)d_out;

    const int N = in_sizes[2];      // 4096
    const int K = in_sizes[1] / N;  // 4096
    const int M = in_sizes[0] / K;  // 8192

    char* xp = (char*)d_ws;
    unsigned char* wt = (unsigned char*)d_ws + (size_t)M * K;

    int nvec = (int)(((long long)M * K) / 16);
    pack_x_kernel<<<(nvec + 255) / 256, 256, 0, stream>>>((const int32x4*)x, (int32x4*)xp, nvec);

    dim3 tgrid(N / 64, K / 64);
    transform_w_kernel<<<tgrid, 256, 0, stream>>>(w, wt, K, N);

    int nwg = (M / BM) * (N / BN);  // 512, %8==0
    gemm_i8_mega<<<nwg, 512, 0, stream>>>(xp, (const char*)wt, bias, shiftp, out, M, N, K);
}